// Round 2
// baseline (226.545 us; speedup 1.0000x reference)
//
#include <hip/hip_runtime.h>
#include <hip/hip_bf16.h>
#include <cstdint>
#include <cstddef>

// Problem constants (fixed shapes per reference)
#define NROWS 8192
#define DIM   1024
#define BT    256          // square tile 256x256 (m201-class geometry)
#define BK    64           // K depth per pipeline stage; 16 stages
#define NKT   (DIM / BK)
#define NFULL 496          // 31*32/2 strictly-lower full tiles (8 XCDs x 62)
#define NDIAG 32
#define NBLK  (NFULL + NDIAG)   // 528; diagonal tiles dispatched LAST (cheap tail)
#define EPS 1e-8f
// E pre-scaled by sqrt(10*log2(e)) so MFMA accumulates 10*log2(e)*<a,b>;
// epilogue is a bare exp2f.
#define PRESCALE 3.798288f

// LDS: 2 buffers x (A 256x64 + B 256x64) bf16 = 2 x 64 KB = 128 KB
#define ABUF_E 16384       // elems per A (or B) K-tile
#define BUF_E  32768       // elems per buffer (A ++ B)

typedef short  bf16x8  __attribute__((ext_vector_type(8)));
typedef float  floatx4 __attribute__((ext_vector_type(4)));

typedef __attribute__((address_space(1))) const void CGV;
typedef __attribute__((address_space(3))) void LV;

__device__ __forceinline__ void async_load16(const void* g, void* l) {
    __builtin_amdgcn_global_load_lds((CGV*)g, (LV*)l, 16, 0, 0);
}

__device__ __forceinline__ unsigned short f2bf_rne(float f) {
    union { float f; unsigned u; } c; c.f = f;
    unsigned u = c.u;
    unsigned r = (u + 0x7fffu + ((u >> 16) & 1u)) >> 16;
    return (unsigned short)r;
}

// ---------------------------------------------------------------------------
// Kernel A: fp32 -> bf16 (RNE) with PRESCALE folded in. First 64 blocks also
// zero the 16384-float accumulator region.
// ---------------------------------------------------------------------------
__global__ __launch_bounds__(256) void convert_kernel(
    const float* __restrict__ in, unsigned short* __restrict__ out,
    float* __restrict__ accum /* all_sum ++ pos_sum, 2*NROWS floats */)
{
    int i = (blockIdx.x * 256 + threadIdx.x) * 4;
    float4 v = *(const float4*)(in + i);
    ushort4 o;
    o.x = f2bf_rne(v.x * PRESCALE);
    o.y = f2bf_rne(v.y * PRESCALE);
    o.z = f2bf_rne(v.z * PRESCALE);
    o.w = f2bf_rne(v.w * PRESCALE);
    *(ushort4*)(out + i) = o;
    if (blockIdx.x < (2 * NROWS) / 256)
        accum[blockIdx.x * 256 + threadIdx.x] = 0.0f;
}

// ---------------------------------------------------------------------------
// Kernel B: symmetric-half fused GEMM, fat-iteration 256x256 / BK=64 pipeline.
// R1 post-mortem: BK=32 thin phases (16 MFMA/barrier) + broken ^(row&3)
// swizzle (8.65M conflicts) = 26% MfmaUtil. Fix: m201-class geometry —
// 8 waves x (128x64 out, acc[8][4]), BK=64 (restores the R3/R9/R11-verified
// conflict-free ^(row&7) chunk swizzle at 128B rows), 64 MFMA + 24 ds_read
// per barrier pair, compiler-interleaved (fine lgkmcnt).
// Counted-vmcnt pipeline with derived, airtight waits:
//   iter kt: [reads+MFMA from buf d=kt&1] -> s_barrier  (ALL waves' reads of
//   buf d consumed — MFMA issue implies read complete) -> STAGE kt+2 -> buf d
//   -> vmcnt(8) retires kt+1 (kt+2's 8 loads/thread stay in flight ACROSS the
//   barrier; never drained to 0 in steady state) -> s_barrier.
// Triangle cover: 496 strictly-lower full tiles (a>c) first, XCD-chunked;
// 32 diagonal tiles LAST with per-frag skip of strictly-upper 16x16 frags
// (wave->(wm,wn) remap balances live frags to max 36/64 per SIMD), so the
// 16 tail CUs run 2 cheap diag blocks each: makespan ~2.2T not 3T.
// UNIFORM symmetry: element (grow,gcol) counts iff grow > gcol; feeds row
// grow AND col gcol (R11-verified); skipped diag frags stay 0 and are masked
// by the same rule, so the epilogue is identical for all blocks.
// ---------------------------------------------------------------------------
__global__ __launch_bounds__(512, 2) void gemm_fused_kernel(
    const unsigned short* __restrict__ E,   // bf16 bits (prescaled), [NROWS][DIM]
    const int*            __restrict__ labels,
    float*                __restrict__ all_sum,
    float*                __restrict__ pos_sum)
{
    __shared__ __align__(16) unsigned short S[2 * BUF_E];   // 128 KB

    const int tid  = threadIdx.x;
    const int lane = tid & 63;
    const int w    = tid >> 6;      // wave 0..7
    // wave -> (row-half wm, col-quarter wn): bijection chosen so SIMD pairs
    // {w, w+4} balance diag-block live-frag counts (32/32/36/36 of 64).
    const int wm   = (w < 4) ? 1 : 0;
    const int wn   = (w < 4) ? w : ((0x0132 >> ((w & 3) * 4)) & 0xF);
    const int colw = lane & 15;
    const int quad = lane >> 4;
    const int swz  = colw & 7;

    // Tile decode: b<NFULL -> strictly-lower full tile, XCD-chunked order;
    // b>=NFULL -> diagonal tile p (dispatched last => cheap tail fill).
    const int b = blockIdx.x;
    int rBase, cBase; bool isDiag;
    if (b < NFULL) {
        const int t = (b & 7) * 62 + (b >> 3);      // 496 = 8 x 62
        int a = (int)((1.0f + sqrtf(1.0f + 8.0f * (float)t)) * 0.5f);
        while (a * (a - 1) / 2 > t) --a;
        while ((a + 1) * a / 2 <= t) ++a;
        const int c = t - a * (a - 1) / 2;          // c < a
        rBase = a * BT; cBase = c * BT; isDiag = false;
    } else {
        const int p = b - NFULL;
        rBase = p * BT; cBase = rBase; isDiag = true;
    }

    // Staging: per K-tile, A = 256x64 = 2048 chunks of 16B, B same; 512
    // threads x (4 A + 4 B). Wave w instr j writes LDS rows w*32+j*8..+8
    // linearly (wave-uniform base + lane*16, m104); the ^(row&7) swizzle is
    // applied on the GLOBAL source chunk (m173): gch = (lane&7) ^ (row&7).
    const int l8  = lane >> 3;                     // row within 8-row group
    const int gch = (lane & 7) ^ l8;               // pre-swizzled global chunk
    const unsigned short* gA0 = E + (size_t)(rBase + w * 32 + l8) * DIM + gch * 8;
    const unsigned short* gB0 = E + (size_t)(cBase + w * 32 + l8) * DIM + gch * 8;
    const int aL = w * 2048 + lane * 8;            // lds elem base, +j*512

    floatx4 acc[8][4];
    #pragma unroll
    for (int i = 0; i < 8; ++i)
        #pragma unroll
        for (int j = 0; j < 4; ++j)
            acc[i][j] = (floatx4)0.0f;

#define STAGE(T, SB) do {                                                     \
        const unsigned short* _ga = gA0 + (T) * BK;                           \
        const unsigned short* _gb = gB0 + (T) * BK;                           \
        unsigned short* _la = &S[(SB) * BUF_E + aL];                          \
        unsigned short* _lb = &S[(SB) * BUF_E + ABUF_E + aL];                 \
        _Pragma("unroll")                                                     \
        for (int j = 0; j < 4; ++j) {                                         \
            async_load16(_ga + j * (8 * DIM), _la + j * 512);                 \
            async_load16(_gb + j * (8 * DIM), _lb + j * 512);                 \
        }                                                                     \
    } while (0)

// Per-iteration body. Reads+MFMA are left to the compiler's fine-grained
// lgkmcnt scheduling (m97 finding: near-optimal). Barrier #1 is reached only
// after every wave's MFMAs issued => all its ds_reads of buf d completed =>
// safe to overwrite buf d. vmcnt(8) retires the PREVIOUS tile's 8 loads;
// the just-issued 8 stay in flight across barrier #2 (T4, counted).
#define KLOOP(MASKCHECK)                                                      \
    for (int kt = 0; kt < NKT; ++kt) {                                        \
        const int bb = (kt & 1) * BUF_E;                                      \
        _Pragma("unroll")                                                     \
        for (int ksub = 0; ksub < 2; ++ksub) {                                \
            const int cs = (((ksub << 2) | quad) ^ swz) << 3;                 \
            bf16x8 bF[4], aF[8];                                              \
            _Pragma("unroll")                                                 \
            for (int nt = 0; nt < 4; ++nt)                                    \
                bF[nt] = *(const bf16x8*)&S[bb + ABUF_E +                     \
                              (wn * 64 + nt * 16 + colw) * BK + cs];          \
            _Pragma("unroll")                                                 \
            for (int mt = 0; mt < 8; ++mt)                                    \
                aF[mt] = *(const bf16x8*)&S[bb +                              \
                              (wm * 128 + mt * 16 + colw) * BK + cs];         \
            __builtin_amdgcn_s_setprio(1);                                    \
            _Pragma("unroll")                                                 \
            for (int mt = 0; mt < 8; ++mt)                                    \
                _Pragma("unroll")                                             \
                for (int nt = 0; nt < 4; ++nt)                                \
                    if (MASKCHECK)                                            \
                        acc[mt][nt] = __builtin_amdgcn_mfma_f32_16x16x32_bf16(\
                            aF[mt], bF[nt], acc[mt][nt], 0, 0, 0);            \
            __builtin_amdgcn_s_setprio(0);                                    \
        }                                                                     \
        __builtin_amdgcn_sched_barrier(0);                                    \
        __builtin_amdgcn_s_barrier();      /* all reads of buf d done */      \
        __builtin_amdgcn_sched_barrier(0);                                    \
        if (kt < NKT - 2) {                                                   \
            STAGE(kt + 2, kt & 1);                                            \
            asm volatile("s_waitcnt vmcnt(8)" ::: "memory");                  \
        } else {                                                              \
            asm volatile("s_waitcnt vmcnt(0)" ::: "memory");                  \
        }                                                                     \
        __builtin_amdgcn_s_barrier();      /* kt+1 visible to all */          \
        __builtin_amdgcn_sched_barrier(0);                                    \
    }

    // Prologue: tiles 0 and 1 in flight; retire tile 0 (oldest 8), keep
    // tile 1's 8 loads in flight across the barrier.
    STAGE(0, 0);
    STAGE(1, 1);
    asm volatile("s_waitcnt vmcnt(8)" ::: "memory");
    __builtin_amdgcn_s_barrier();
    __builtin_amdgcn_sched_barrier(0);

    if (!isDiag) {
        KLOOP(true)
    } else {
        // Skip 16x16 frags that are entirely strictly-upper (max row < min col).
        KLOOP(wm * 128 + mt * 16 + 15 >= wn * 64 + nt * 16)
    }
#undef KLOOP
#undef STAGE

    // Epilogue. C/D layout (16x16x32): col = lane&15, row = quad*4 + reg.
    // Uniform rule: element (grow, gcol) counts iff grow > gcol; contributes
    // to row grow AND col gcol (R11-verified). Skipped diag frags hold 0 and
    // are masked by the same rule.
    float labc[4];
    int   gcolv[4];
    #pragma unroll
    for (int nt = 0; nt < 4; ++nt) {
        gcolv[nt] = cBase + wn * 64 + nt * 16 + colw;
        labc[nt]  = (float)labels[gcolv[nt]];
    }

    float colAll[4] = {0.f, 0.f, 0.f, 0.f};
    float colPos[4] = {0.f, 0.f, 0.f, 0.f};

    #pragma unroll
    for (int mt = 0; mt < 8; ++mt) {
        const int growBase = rBase + wm * 128 + mt * 16 + quad * 4;
        #pragma unroll
        for (int r = 0; r < 4; ++r) {
            const int grow = growBase + r;
            const float labr = (float)labels[grow];
            float sAll = 0.f, sPos = 0.f;
            #pragma unroll
            for (int nt = 0; nt < 4; ++nt) {
                float ev = exp2f(acc[mt][nt][r]);   // PRESCALE folded into E
                ev = (grow > gcolv[nt]) ? ev : 0.0f; // strictly-lower only
                sAll += ev;
                sPos += ev * labc[nt];
                colAll[nt] += ev;
                colPos[nt] += ev * labr;
            }
            // row-reduce across the 16 lanes (same quad) sharing this row
            #pragma unroll
            for (int off = 1; off < 16; off <<= 1) {
                sAll += __shfl_xor(sAll, off);
                sPos += __shfl_xor(sPos, off);
            }
            if (colw == 0 && sAll != 0.f) {
                atomicAdd(&all_sum[grow], sAll);
                atomicAdd(&pos_sum[grow], sPos);
            }
        }
    }

    // col-reduce: sum across quads (lanes differing in bits 4,5)
    #pragma unroll
    for (int nt = 0; nt < 4; ++nt) {
        float aa = colAll[nt], p = colPos[nt];
        aa += __shfl_xor(aa, 16);  p += __shfl_xor(p, 16);
        aa += __shfl_xor(aa, 32);  p += __shfl_xor(p, 32);
        if (quad == 0 && aa != 0.f) {
            atomicAdd(&all_sum[gcolv[nt]], aa);
            atomicAdd(&pos_sum[gcolv[nt]], p);
        }
    }
}

// ---------------------------------------------------------------------------
// Kernel C: loss = mean over rows with lab==1 of -log(pos/(all+eps)); 0 if n_ref<2
// ---------------------------------------------------------------------------
__global__ __launch_bounds__(1024) void finalize_kernel(
    const float* __restrict__ all_sum,
    const float* __restrict__ pos_sum,
    const int*   __restrict__ labels,
    float*       __restrict__ out)
{
    __shared__ float sSum[1024];
    __shared__ float sCnt[1024];
    const int tid = threadIdx.x;
    float lsum = 0.f, lcnt = 0.f;
    for (int i = tid; i < NROWS; i += 1024) {
        if (labels[i] > 0) {
            float p = pos_sum[i];
            float a = all_sum[i] + EPS;
            lsum += -logf(p / a);
            lcnt += 1.0f;
        }
    }
    sSum[tid] = lsum;
    sCnt[tid] = lcnt;
    __syncthreads();
    for (int s = 512; s > 0; s >>= 1) {
        if (tid < s) { sSum[tid] += sSum[tid + s]; sCnt[tid] += sCnt[tid + s]; }
        __syncthreads();
    }
    if (tid == 0) {
        float n = sCnt[0];
        out[0] = (n < 2.0f) ? 0.0f : sSum[0] / fmaxf(n, 1.0f);
    }
}

// ---------------------------------------------------------------------------
extern "C" void kernel_launch(void* const* d_in, const int* in_sizes, int n_in,
                              void* d_out, int out_size, void* d_ws, size_t ws_size,
                              hipStream_t stream) {
    const float* emb    = (const float*)d_in[0];
    const int*   labels = (const int*)d_in[1];
    float*       out    = (float*)d_out;

    // workspace layout: [bf16 E: 16 MB][all_sum: 32 KB][pos_sum: 32 KB]
    unsigned short* Ebf = (unsigned short*)d_ws;
    const size_t embBytes = (size_t)NROWS * DIM * sizeof(unsigned short);
    float* all_sum = (float*)((char*)d_ws + embBytes);
    float* pos_sum = all_sum + NROWS;

    convert_kernel<<<(NROWS * DIM) / (4 * 256), 256, 0, stream>>>(emb, Ebf, all_sum);

    gemm_fused_kernel<<<NBLK, 512, 0, stream>>>(Ebf, labels, all_sum, pos_sum);

    finalize_kernel<<<1, 1024, 0, stream>>>(all_sum, pos_sum, labels, out);
}